// Round 1
// 320.439 us; speedup vs baseline: 1.0015x; 1.0015x over previous
//
#include <hip/hip_runtime.h>
#include <hip/hip_bf16.h>
#include <math.h>

// Sizes (fixed by the reference)
#define GG   4096
#define NNODE 64
#define EEDGE 256
#define FFEAT 64
#define DDIM 128
#define EP   32768

// ---------------------------------------------------------------------------
// Prep (once per call, tiny): Wgf1' = relayout(Wg @ Wf1) [64x16],
// stored as W'[(kk*4+q)*16 + j] = (Wg@Wf1)[q*16+kk][j]  (bank-friendly for
// the per-lane q-split read in k_pg P5).
// bcomb = bg @ Wf1 + bf1 [16], bg32 = 32*bg [128]. Also zeroes icnt_g
// (replaces the hipMemsetAsync dispatch).
// ---------------------------------------------------------------------------
__global__ void k_prep(const float* __restrict__ Wg, const float* __restrict__ Wf1,
                       const float* __restrict__ bf1, const float* __restrict__ bg,
                       float* __restrict__ Wgf1, float* __restrict__ bcomb,
                       float* __restrict__ bg32, int* __restrict__ icnt_g) {
    int t = threadIdx.x;
    for (int o = t; o < 1024; o += 256) {
        int r = o >> 4, j = o & 15;
        int kk = r >> 2, q = r & 3;
        int f = q * 16 + kk;          // original row of Wg@Wf1
        float s = 0.f;
        for (int d = 0; d < 128; ++d) s += Wg[f * 128 + d] * Wf1[d * 16 + j];
        Wgf1[o] = s;
    }
    if (t < 16) {
        float s = bf1[t];
        for (int d = 0; d < 128; ++d) s += bg[d] * Wf1[d * 16 + t];
        bcomb[t] = s;
    }
    if (t >= 128) bg32[t - 128] = 32.0f * bg[t - 128];
    for (int i = t; i < 4096; i += 256) icnt_g[i] = 0;
}

// ---------------------------------------------------------------------------
// Per-graph kernel, round-8 rewrite. Previous version: 4 blocks/CU
// (LDS 34.3 KB), ~12 barriers, P5 issuing 80 ds_read_b128/thread ->
// latency + LDS-pipe bound (VALUBusy 22%, occ 38%).
// This version:
//  * own-edge data (src/dst/w/lw) lives in registers (P1/P3/P8 need only
//    the thread's own edge) -> srcs/dsts/lwx deleted from LDS
//  * P4's gathered row Av[16] stays in registers and feeds P5 directly
//  * P5+P6+P7 merged: per-thread partial over 16 k's, 4-lane shfl_xor
//    reduce, tanh+logits+softmax in registers -> a1s round-trip deleted,
//    64 (not 80) ds_read_b128/thread, 2 fewer barriers
//  * Ssum == 1 exactly (softmax rows sum to 1) -> Qh = 0.5*sum_n xa[n]
//  * LDS 26.6 KB -> 6 blocks/CU (24 waves/CU)
// ---------------------------------------------------------------------------
__global__ __launch_bounds__(256) void k_pg(
    const float* __restrict__ x, const int* __restrict__ ei, const float* __restrict__ ew,
    const float* __restrict__ Wgf1, const float* __restrict__ bcomb,
    const float* __restrict__ Wf2, const float* __restrict__ bf2,
    float* __restrict__ Qh, float* __restrict__ pens)
{
    __shared__ __align__(16) float sm[6656];
    float* xs    = sm;                    // 64x68; holds x, then (in place) xa
    float* Wp    = sm + 4352;             // 1024 W' (reused as Qh partials in P9)
    int*   lsrc  = (int*)(sm + 5376);     // 256 CSR src
    float* lnrm  = sm + 5632;             // 256 CSR norm
    int*   icnt  = (int*)(sm + 5888);     // 64
    int*   offs  = (int*)(sm + 5952);     // 64
    int*   curs  = (int*)(sm + 6016);     // 64
    float* degw  = sm + 6080;             // 64
    float* dinvs = sm + 6144;             // 64
    float* deg2s = sm + 6208;             // 64
    float* dinv2s= sm + 6272;             // 64
    float* Ss    = sm + 6336;             // 128
    float* LSs   = sm + 6464;             // 128
    float* bcs   = sm + 6592;             // 16
    float* Wf2s  = sm + 6608;             // 32
    float* bf2s  = sm + 6640;             // 2

    const int g = blockIdx.x;
    const int t = threadIdx.x;
    const float* xg = x + (size_t)g * 4096;

    // P0: stage x, W', consts; own edge -> registers; zero counters
    int es, ed; float wv;
    {
        const int* eg = ei + (size_t)g * 512;
        es = eg[t];
        ed = eg[256 + t];
        wv = ew[(size_t)g * 256 + t];
        for (int i = t; i < 1024; i += 256) {
            int n = i >> 4, k = (i & 15) * 4;
            *(float4*)&xs[n * 68 + k] = *(const float4*)&xg[n * 64 + k];
        }
        *(float4*)&Wp[t * 4] = *(const float4*)&Wgf1[t * 4];
        if (t < 16) bcs[t] = bcomb[t];
        if (t < 32) Wf2s[t] = Wf2[t];
        if (t < 2)  bf2s[t] = bf2[t];
        if (t < 64) { icnt[t] = 0; degw[t] = 1.0f; deg2s[t] = 0.0f; }
        if (t < 128) LSs[t] = 0.0f;
    }
    __syncthreads();

    // P1: counts + weighted degrees (own-edge registers)
    atomicAdd(&icnt[ed], 1);
    atomicAdd(&degw[ed], wv);
    atomicAdd(&deg2s[es], wv);
    __syncthreads();

    // P2: wave0 scans counts -> offsets; dinv
    if (t < 64) {
        int v = icnt[t], own = v;
        for (int o = 1; o < 64; o <<= 1) { int u = __shfl_up(v, o); if (t >= o) v += u; }
        int excl = v - own;
        offs[t] = excl; curs[t] = excl;
        dinvs[t] = rsqrtf(degw[t]);
        float dg = deg2s[t];
        dinv2s[t] = dg > 0.0f ? rsqrtf(fmaxf(dg, 1e-30f)) : 0.0f;
    }
    __syncthreads();

    // P3: place edge into CSR; laplacian weight stays in a register
    float lw;
    {
        int pos = atomicAdd(&curs[ed], 1);
        lsrc[pos] = es;
        lnrm[pos] = dinvs[es] * wv * dinvs[ed];
        lw = -dinv2s[es] * wv * dinv2s[ed];
    }
    __syncthreads();

    // P4: gather xa[n] = x[n]*dinv^2 + sum_{e->n} x[src]*nrm into REGISTERS
    // (Av[16]), write back in place over xs; Av feeds P5 directly.
    const int n = t >> 2, q = t & 3, base = q * 16;
    float Av[16];
    {
        float sc = dinvs[n] * dinvs[n];
        const float* xrow = &xs[n * 68 + base];
        *(float4*)&Av[0]  = *(const float4*)&xrow[0];
        *(float4*)&Av[4]  = *(const float4*)&xrow[4];
        *(float4*)&Av[8]  = *(const float4*)&xrow[8];
        *(float4*)&Av[12] = *(const float4*)&xrow[12];
#pragma unroll
        for (int kk = 0; kk < 16; ++kk) Av[kk] *= sc;
        int o = offs[n], c = icnt[n];
        for (int j = 0; j < c; ++j) {
            int s = lsrc[o + j];
            float nm = lnrm[o + j];
            const float* xr = &xs[s * 68 + base];
            float4 X0 = *(const float4*)&xr[0];
            float4 X1 = *(const float4*)&xr[4];
            float4 X2 = *(const float4*)&xr[8];
            float4 X3 = *(const float4*)&xr[12];
            Av[0]  += X0.x * nm; Av[1]  += X0.y * nm; Av[2]  += X0.z * nm; Av[3]  += X0.w * nm;
            Av[4]  += X1.x * nm; Av[5]  += X1.y * nm; Av[6]  += X1.z * nm; Av[7]  += X1.w * nm;
            Av[8]  += X2.x * nm; Av[9]  += X2.y * nm; Av[10] += X2.z * nm; Av[11] += X2.w * nm;
            Av[12] += X3.x * nm; Av[13] += X3.y * nm; Av[14] += X3.z * nm; Av[15] += X3.w * nm;
        }
        __syncthreads();   // all reads of x (in xs) complete
        float* xw = &xs[n * 68 + base];
        *(float4*)&xw[0]  = *(float4*)&Av[0];
        *(float4*)&xw[4]  = *(float4*)&Av[4];
        *(float4*)&xw[8]  = *(float4*)&Av[8];
        *(float4*)&xw[12] = *(float4*)&Av[12];
    }
    __syncthreads();       // xa (in xs) visible

    // P5+P6+P7 merged: a1 = tanh(xa @ Wgf1 + bcomb) -> logits -> softmax,
    // fully in registers. Thread (n,q) accumulates over its 16 k's for all
    // 16 j's, then 2-round shfl_xor reduce across the 4-lane group.
    // W' layout: row (kk*4+q) -> 2-way bank alias only (free).
    {
        float pj[16];
#pragma unroll
        for (int j = 0; j < 16; ++j) pj[j] = 0.f;
#pragma unroll
        for (int kk = 0; kk < 16; ++kk) {
            float a = Av[kk];
            const float* wr = &Wp[((kk << 2) + q) << 4];
            float4 w0 = *(const float4*)&wr[0];
            float4 w1 = *(const float4*)&wr[4];
            float4 w2 = *(const float4*)&wr[8];
            float4 w3 = *(const float4*)&wr[12];
            pj[0]  += a * w0.x; pj[1]  += a * w0.y; pj[2]  += a * w0.z; pj[3]  += a * w0.w;
            pj[4]  += a * w1.x; pj[5]  += a * w1.y; pj[6]  += a * w1.z; pj[7]  += a * w1.w;
            pj[8]  += a * w2.x; pj[9]  += a * w2.y; pj[10] += a * w2.z; pj[11] += a * w2.w;
            pj[12] += a * w3.x; pj[13] += a * w3.y; pj[14] += a * w3.z; pj[15] += a * w3.w;
        }
#pragma unroll
        for (int j = 0; j < 16; ++j) {
            pj[j] += __shfl_xor(pj[j], 1);
            pj[j] += __shfl_xor(pj[j], 2);
        }
        float z0 = bf2s[0], z1 = bf2s[1];
#pragma unroll
        for (int j = 0; j < 16; ++j) {
            float aj = tanhf(pj[j] + bcs[j]);
            z0 += aj * Wf2s[2 * j];
            z1 += aj * Wf2s[2 * j + 1];
        }
        float m = fmaxf(z0, z1);
        float e0 = expf(z0 - m), e1 = expf(z1 - m);
        float inv = 1.0f / (e0 + e1);
        if (q == 0) { Ss[n * 2] = e0 * inv; Ss[n * 2 + 1] = e1 * inv; }
    }
    __syncthreads();

    // P8: LS scatter (own-edge registers; identity added at use)
    {
        float s0 = Ss[ed * 2], s1 = Ss[ed * 2 + 1];
        atomicAdd(&LSs[es * 2],     lw * s0);
        atomicAdd(&LSs[es * 2 + 1], lw * s1);
    }
    __syncthreads();

    // P9: penalty (wave0) + Qh partials (all threads).
    // Qh[g,k] = 0.5 * sum_n xa[n,k]   (softmax row-sums are exactly 1).
    if (t < 64) {
        float s0 = Ss[t * 2], s1 = Ss[t * 2 + 1];
        float l0 = s0 + LSs[t * 2], l1 = s1 + LSs[t * 2 + 1];
        float p00 = s0 * l0, p01 = s0 * l1, p10 = s1 * l0, p11 = s1 * l1;
        for (int o = 32; o; o >>= 1) {
            p00 += __shfl_down(p00, o); p01 += __shfl_down(p01, o);
            p10 += __shfl_down(p10, o); p11 += __shfl_down(p11, o);
        }
        if (t == 0) {
            float r0 = fmaxf(fabsf(p00) + fabsf(p01), 1e-12f);
            float r1 = fmaxf(fabsf(p10) + fabsf(p11), 1e-12f);
            float d0 = p00 / r0 - 1.0f, d1 = p11 / r1 - 1.0f;
            pens[g] = 0.5f * (d0 * d0 + d1 * d1);
        }
    }
    {
        int k = t & 63, p = t >> 6;
        float qk = 0.f;
#pragma unroll 4
        for (int nn = 0; nn < 16; ++nn)
            qk += xs[(p * 16 + nn) * 68 + k];
        Wp[p * 64 + k] = qk;   // Wp reads finished before the Ss barrier
    }
    __syncthreads();
    if (t < 64)
        Qh[(size_t)g * 64 + t] = 0.5f * (Wp[t] + Wp[64 + t] + Wp[128 + t] + Wp[192 + t]);
}

// ---------------------------------------------------------------------------
// Parallel CSR build over pos_edges (3 small kernels; round-6 showed the
// merged single-block version serializes on one CU).
// ---------------------------------------------------------------------------
__global__ void k_cnt(const int* __restrict__ pd, int* __restrict__ icnt) {
    int e = blockIdx.x * 256 + threadIdx.x;
    atomicAdd(&icnt[pd[e]], 1);
}

__global__ void k_scan(const int* __restrict__ icnt, int* __restrict__ offs,
                       int* __restrict__ curs, float* __restrict__ dinv) {
    __shared__ int wsum[4];
    int t = threadIdx.x;
    int base = t * 16;
    int l0,l1,l2,l3,l4,l5,l6,l7,l8,l9,l10,l11,l12,l13,l14,l15;
    l0=icnt[base+0]; l1=icnt[base+1]; l2=icnt[base+2]; l3=icnt[base+3];
    l4=icnt[base+4]; l5=icnt[base+5]; l6=icnt[base+6]; l7=icnt[base+7];
    l8=icnt[base+8]; l9=icnt[base+9]; l10=icnt[base+10]; l11=icnt[base+11];
    l12=icnt[base+12]; l13=icnt[base+13]; l14=icnt[base+14]; l15=icnt[base+15];
    int s = l0+l1+l2+l3+l4+l5+l6+l7+l8+l9+l10+l11+l12+l13+l14+l15;
    int lane = t & 63, w = t >> 6;
    int v = s;
    for (int o = 1; o < 64; o <<= 1) { int u = __shfl_up(v, o); if (lane >= o) v += u; }
    if (lane == 63) wsum[w] = v;
    __syncthreads();
    int woff = 0;
    for (int i = 0; i < 4; ++i) if (i < w) woff += wsum[i];
    int run = woff + v - s;
#define SC(L, I) offs[base+(I)] = run; curs[base+(I)] = run; \
    dinv[base+(I)] = rsqrtf((float)(L) + 1.0f); run += L;
    SC(l0,0) SC(l1,1) SC(l2,2) SC(l3,3) SC(l4,4) SC(l5,5) SC(l6,6) SC(l7,7)
    SC(l8,8) SC(l9,9) SC(l10,10) SC(l11,11) SC(l12,12) SC(l13,13) SC(l14,14) SC(l15,15)
#undef SC
}

__global__ void k_place(const int* __restrict__ pe, const float* __restrict__ dinv,
                        int* __restrict__ curs, int* __restrict__ csr_src,
                        float* __restrict__ csr_nrm) {
    int e = blockIdx.x * 256 + threadIdx.x;
    int s = pe[e], d = pe[EP + e];
    int pos = atomicAdd(&curs[d], 1);
    csr_src[pos] = s;
    csr_nrm[pos] = dinv[s] * dinv[d];
}

// ---------------------------------------------------------------------------
// CSR gathers: out[g] = in[g]*dinv[g]^2 + sum_{edges->g} in[src]*nrm.
// ---------------------------------------------------------------------------
__global__ void k_gather128(const int* __restrict__ offs, const int* __restrict__ icnt,
                            const int* __restrict__ csr_src, const float* __restrict__ csr_nrm,
                            const float* __restrict__ dinv, const float* __restrict__ in,
                            float* __restrict__ out) {
    int g = blockIdx.x, d = threadIdx.x;  // 128 threads
    float dv = dinv[g];
    float acc = in[(size_t)g * 128 + d] * dv * dv;
    int o = offs[g], c = icnt[g];
    for (int j = 0; j < c; ++j)
        acc += in[(size_t)csr_src[o + j] * 128 + d] * csr_nrm[o + j];
    out[(size_t)g * 128 + d] = acc;
}

__global__ void k_gather256(const int* __restrict__ offs, const int* __restrict__ icnt,
                            const int* __restrict__ csr_src, const float* __restrict__ csr_nrm,
                            const float* __restrict__ dinv, const float* __restrict__ in,
                            float* __restrict__ out) {
    int g = blockIdx.x, d = threadIdx.x;  // 256 threads
    float dv = dinv[g];
    float acc = in[(size_t)g * 256 + d] * dv * dv;
    int o = offs[g], c = icnt[g];
    for (int j = 0; j < c; ++j)
        acc += in[(size_t)csr_src[o + j] * 256 + d] * csr_nrm[o + j];
    out[(size_t)g * 256 + d] = acc;
}

// ---------------------------------------------------------------------------
// Double-buffered tiled fp32 GEMM (unchanged): 64x64 tile, 256 threads,
// 4x4 microtile, BK=32, register-prefetch + 2x LDS buffers.
// Dual-output option: blockIdx.y >= gridDim.y/2 uses B1/bias1/C1 (shared A).
// ---------------------------------------------------------------------------
__global__ __launch_bounds__(256) void k_gemm(
    const float* __restrict__ A,
    const float* __restrict__ B0, const float* __restrict__ bias0, float* __restrict__ C0,
    const float* __restrict__ B1, const float* __restrict__ bias1, float* __restrict__ C1,
    int M, int K, int N, int dorelu)
{
    __shared__ __align__(16) float lds[2 * 4352];
    const float* B = B0; const float* bias = bias0; float* C = C0;
    int by = blockIdx.y;
    if (B1 != nullptr && by >= (int)(gridDim.y >> 1)) {
        B = B1; bias = bias1; C = C1; by -= (gridDim.y >> 1);
    }
    const int mb = blockIdx.x * 64, nbb = by * 64;
    const int t = threadIdx.x;
    const int tm4 = (t >> 4) * 4, tn4 = (t & 15) * 4;
    const int ma = t >> 2, ka = (t & 3) * 8;
    const int kb = t >> 3, nb8 = (t & 7) * 8;

    float4 pa0, pa1, pb0, pb1;
#define LOADT(K0) { \
    const float* Ap = &A[(size_t)(mb + ma) * K + (K0) + ka]; \
    pa0 = *(const float4*)Ap; pa1 = *(const float4*)(Ap + 4); \
    const float* Bp = &B[(size_t)((K0) + kb) * N + nbb + nb8]; \
    pb0 = *(const float4*)Bp; pb1 = *(const float4*)(Bp + 4); }
#define STORET(BUF) { \
    float* At_ = lds + (BUF) * 4352; \
    At_[(ka + 0) * 68 + ma] = pa0.x; At_[(ka + 1) * 68 + ma] = pa0.y; \
    At_[(ka + 2) * 68 + ma] = pa0.z; At_[(ka + 3) * 68 + ma] = pa0.w; \
    At_[(ka + 4) * 68 + ma] = pa1.x; At_[(ka + 5) * 68 + ma] = pa1.y; \
    At_[(ka + 6) * 68 + ma] = pa1.z; At_[(ka + 7) * 68 + ma] = pa1.w; \
    float* Bs_ = lds + (BUF) * 4352 + 2176; \
    *(float4*)&Bs_[kb * 68 + nb8] = pb0; *(float4*)&Bs_[kb * 68 + nb8 + 4] = pb1; }

    float4 ca0 = {0,0,0,0}, ca1 = {0,0,0,0}, ca2 = {0,0,0,0}, ca3 = {0,0,0,0};
    const int nk0 = K >> 5;
    LOADT(0)
    STORET(0)
    __syncthreads();
    for (int it = 0; it < nk0; ++it) {
        if (it + 1 < nk0) LOADT((it + 1) * 32)
        const float* At_ = lds + (it & 1) * 4352;
        const float* Bs_ = At_ + 2176;
#pragma unroll
        for (int k = 0; k < 32; ++k) {
            float4 av = *(const float4*)&At_[k * 68 + tm4];
            float4 bv = *(const float4*)&Bs_[k * 68 + tn4];
            ca0.x += av.x * bv.x; ca0.y += av.x * bv.y; ca0.z += av.x * bv.z; ca0.w += av.x * bv.w;
            ca1.x += av.y * bv.x; ca1.y += av.y * bv.y; ca1.z += av.y * bv.z; ca1.w += av.y * bv.w;
            ca2.x += av.z * bv.x; ca2.y += av.z * bv.y; ca2.z += av.z * bv.z; ca2.w += av.z * bv.w;
            ca3.x += av.w * bv.x; ca3.y += av.w * bv.y; ca3.z += av.w * bv.z; ca3.w += av.w * bv.w;
        }
        if (it + 1 < nk0) {
            STORET((it + 1) & 1)
            __syncthreads();
        }
    }
#undef LOADT
#undef STORET
    float4 bv4 = {0, 0, 0, 0};
    if (bias) bv4 = *(const float4*)&bias[nbb + tn4];
#define CST(I, CV) { \
    float4 v; v.x = CV.x + bv4.x; v.y = CV.y + bv4.y; v.z = CV.z + bv4.z; v.w = CV.w + bv4.w; \
    if (dorelu) { v.x = fmaxf(v.x, 0.f); v.y = fmaxf(v.y, 0.f); v.z = fmaxf(v.z, 0.f); v.w = fmaxf(v.w, 0.f); } \
    *(float4*)&C[(size_t)(mb + tm4 + (I)) * N + nbb + tn4] = v; }
    CST(0, ca0) CST(1, ca1) CST(2, ca2) CST(3, ca3)
#undef CST
}

// z = mu + eps*exp(min(ls,10)); zc = [emb, z]; per-graph KL partial
__global__ void k_fin_z(const float* __restrict__ mu_arr, const float* __restrict__ ls_arr,
                        const float* __restrict__ eps, const float* __restrict__ emb,
                        float* __restrict__ zc, float* __restrict__ klp) {
    __shared__ float smw[2];
    int g = blockIdx.x, d = threadIdx.x;  // 128 threads
    int idx = g * 128 + d;
    float mu = mu_arr[idx];
    float ls = fminf(ls_arr[idx], 10.0f);
    float z = mu + eps[idx] * expf(ls);
    zc[(size_t)g * 256 + d] = emb[idx];
    zc[(size_t)g * 256 + 128 + d] = z;
    float term = 1.0f + 2.0f * ls - mu * mu - expf(2.0f * ls);
    for (int o = 32; o; o >>= 1) term += __shfl_down(term, o);
    if ((d & 63) == 0) smw[d >> 6] = term;
    __syncthreads();
    if (d == 0) klp[g] = smw[0] + smw[1];
}

// Edge predictions, 16 lanes per edge (4 edges in flight per wave, 4-step
// reduce): sigmoid(dot(A[src], B[dst])) + per-block log partial (16 edges).
__global__ void k_pred(const float* __restrict__ A, const float* __restrict__ B,
                       const int* __restrict__ pos, const int* __restrict__ neg,
                       float* __restrict__ out, float* __restrict__ predp) {
    __shared__ float smw[16];
    int t = threadIdx.x, sub = t >> 4, l = t & 15;
    int eg = blockIdx.x * 16 + sub;
    int isneg = eg >= EP;
    int e = eg - (isneg ? EP : 0);
    const int* eix = isneg ? neg : pos;
    int s = eix[e], d = eix[EP + e];
    const float4* Ar = (const float4*)(A + (size_t)s * 256);
    const float4* Br = (const float4*)(B + (size_t)d * 256);
    float dot = 0.f;
#pragma unroll
    for (int q = 0; q < 4; ++q) {
        float4 av = Ar[l + 16 * q], bv = Br[l + 16 * q];
        dot += av.x * bv.x + av.y * bv.y + av.z * bv.z + av.w * bv.w;
    }
    for (int o = 8; o; o >>= 1) dot += __shfl_down(dot, o);
    if (l == 0) {
        float p = 1.0f / (1.0f + expf(-dot));
        float term;
        if (isneg) { out[2 + EP + e] = p; term = logf(1.0f - p + 1e-15f); }
        else       { out[2 + e] = p;      term = logf(p + 1e-15f); }
        smw[sub] = term;
    }
    __syncthreads();
    if (t == 0) {
        float s16 = 0.f;
#pragma unroll
        for (int i = 0; i < 16; ++i) s16 += smw[i];
        predp[blockIdx.x] = s16;
    }
}

// Final scalar reductions (predp now 4096 entries: 2048 pos + 2048 neg)
__global__ void k_final(const float* __restrict__ pens, const float* __restrict__ klp,
                        const float* __restrict__ predp, float* __restrict__ out) {
    __shared__ float sm[16];
    int t = threadIdx.x;
    float s_pen = 0.f, s_kl = 0.f, s_pos = 0.f, s_neg = 0.f;
    for (int i = t; i < 4096; i += 256) { s_pen += pens[i]; s_kl += klp[i]; }
    for (int i = t; i < 2048; i += 256) { s_pos += predp[i]; s_neg += predp[2048 + i]; }
    for (int o = 32; o; o >>= 1) {
        s_pen += __shfl_down(s_pen, o); s_kl += __shfl_down(s_kl, o);
        s_pos += __shfl_down(s_pos, o); s_neg += __shfl_down(s_neg, o);
    }
    int w = t >> 6;
    if ((t & 63) == 0) { sm[w] = s_pen; sm[4 + w] = s_kl; sm[8 + w] = s_pos; sm[12 + w] = s_neg; }
    __syncthreads();
    if (t == 0) {
        float pen = sm[0] + sm[1] + sm[2] + sm[3];
        float kls = sm[4] + sm[5] + sm[6] + sm[7];
        float pos = sm[8] + sm[9] + sm[10] + sm[11];
        float neg = sm[12] + sm[13] + sm[14] + sm[15];
        float rec = -(pos / 32768.0f) - (neg / 32768.0f);
        out[0] = rec - 0.5f * kls / (4096.0f * 4096.0f);
        out[1] = pen * (1.0f / 4096.0f);
    }
}

extern "C" void kernel_launch(void* const* d_in, const int* in_sizes, int n_in,
                              void* d_out, int out_size, void* d_ws, size_t ws_size,
                              hipStream_t stream) {
    const float* x   = (const float*)d_in[0];
    const int*   ei  = (const int*)d_in[1];
    const float* ew  = (const float*)d_in[2];
    const int*   pos = (const int*)d_in[3];
    const int*   neg = (const int*)d_in[4];
    const float* eps = (const float*)d_in[5];
    const float* Wg  = (const float*)d_in[6];
    const float* bg  = (const float*)d_in[7];
    const float* Wf1 = (const float*)d_in[8];
    const float* bf1 = (const float*)d_in[9];
    const float* Wf2 = (const float*)d_in[10];
    const float* bf2 = (const float*)d_in[11];
    const float* Wc1 = (const float*)d_in[12];
    const float* bc1 = (const float*)d_in[13];
    const float* Wmu = (const float*)d_in[14];
    const float* bmu = (const float*)d_in[15];
    const float* Wls = (const float*)d_in[16];
    const float* bls = (const float*)d_in[17];
    const float* emb = (const float*)d_in[18];
    const float* Wl1 = (const float*)d_in[19];
    const float* bl1 = (const float*)d_in[20];
    const float* Wl2 = (const float*)d_in[21];
    const float* bl2 = (const float*)d_in[22];
    float* out = (float*)d_out;
    float* ws  = (float*)d_ws;

    // Workspace layout (floats), ~30.8 MB
    float* g_embs  = ws + 0;         // 524288
    float* dinv    = ws + 524288;    // 4096
    int*   icnt_g  = (int*)(ws + 528384);  // 4096
    int*   off_g   = (int*)(ws + 532480);  // 4096
    int*   cur_g   = (int*)(ws + 536576);  // 4096
    int*   csr_src = (int*)(ws + 540672);  // 32768
    float* csr_nrm = ws + 573440;    // 32768
    float* Qh      = ws + 606208;    // 262144
    float* ga      = ws + 868352;    // 524288
    float* h       = ws + 1392640;   // 1048576
    float* ha      = ws + 2441216;   // 1048576
    float* mu_arr  = ws + 3489792;   // 524288
    float* ls_arr  = ws + 4014080;   // 524288
    float* zc      = ws + 4538368;   // 1048576
    float* Abuf    = ws + 5586944;   // 1048576
    float* Bbuf    = ws + 6635520;   // 1048576
    float* pens    = ws + 7684096;   // 4096
    float* klp     = ws + 7688192;   // 4096
    float* predp   = ws + 7692288;   // 4096
    float* Wgf1    = ws + 7708672;   // 1024
    float* bcomb   = ws + 7709696;   // 16
    float* bg32    = ws + 7709712;   // 128

    // Prep (also zeroes icnt_g -> memset dispatch removed) + per-graph stage
    k_prep<<<1, 256, 0, stream>>>(Wg, Wf1, bf1, bg, Wgf1, bcomb, bg32, icnt_g);
    k_pg<<<GG, 256, 0, stream>>>(x, ei, ew, Wgf1, bcomb, Wf2, bf2, Qh, pens);
    // g_embs = Qh @ Wg + 32*bg
    k_gemm<<<dim3(64, 2), 256, 0, stream>>>(Qh, Wg, bg32, g_embs,
                                            nullptr, nullptr, nullptr, GG, 64, 128, 0);

    // Parallel CSR build over pos_edges
    k_cnt<<<EP / 256, 256, 0, stream>>>(pos + EP, icnt_g);
    k_scan<<<1, 256, 0, stream>>>(icnt_g, off_g, cur_g, dinv);
    k_place<<<EP / 256, 256, 0, stream>>>(pos, dinv, cur_g, csr_src, csr_nrm);

    // h = relu((A g_embs) @ Wc1 + bc1)
    k_gather128<<<GG, 128, 0, stream>>>(off_g, icnt_g, csr_src, csr_nrm, dinv, g_embs, ga);
    k_gemm<<<dim3(64, 4), 256, 0, stream>>>(ga, Wc1, bc1, h,
                                            nullptr, nullptr, nullptr, GG, 128, 256, 1);

    // mu/ls = (A h) @ {Wmu,Wls} + {bmu,bls}
    k_gather256<<<GG, 256, 0, stream>>>(off_g, icnt_g, csr_src, csr_nrm, dinv, h, ha);
    k_gemm<<<dim3(64, 4), 256, 0, stream>>>(ha, Wmu, bmu, mu_arr,
                                            Wls, bls, ls_arr, GG, 256, 128, 0);
    k_fin_z<<<GG, 128, 0, stream>>>(mu_arr, ls_arr, eps, emb, zc, klp);

    // A = zc@W_lin1+b, B = zc@W_lin2+b
    k_gemm<<<dim3(64, 8), 256, 0, stream>>>(zc, Wl1, bl1, Abuf,
                                            Wl2, bl2, Bbuf, GG, 256, 256, 0);

    // Edge predictions + scalars (16 edges/block)
    k_pred<<<(2 * EP) / 16, 256, 0, stream>>>(Abuf, Bbuf, pos, neg, out, predp);
    k_final<<<1, 256, 0, stream>>>(pens, klp, predp, out);
}